// Round 9
// baseline (442.736 us; speedup 1.0000x reference)
//
#include <hip/hip_runtime.h>

#define B_SZ  1024
#define NSEQ  512
#define D_INP 30
#define H     64
#define MB    16
#define TCH   8
#define L2E   1.4426950408889634f

typedef short s16x8 __attribute__((ext_vector_type(8)));
typedef float f32x4 __attribute__((ext_vector_type(4)));

#if __has_builtin(__builtin_amdgcn_exp2f)
#define EXP2(x) __builtin_amdgcn_exp2f(x)
#else
#define EXP2(x) exp2f(x)
#endif

// LDS-only barrier: h exchange needs lgkm ordering, NOT vmcnt(0) drain.
// (__syncthreads emits s_waitcnt vmcnt(0) lgkmcnt(0) -> stalls ~900cyc on
// in-flight HBM x-prefetch every chunk. Global load results are waited at
// their register USE instead.)
#define LDS_BARRIER() asm volatile("s_waitcnt lgkmcnt(0)\n\ts_barrier" ::: "memory")

__device__ __forceinline__ float rcp_f(float v) { return __builtin_amdgcn_rcpf(v); }

__device__ __forceinline__ f32x4 mfma16(s16x8 a, s16x8 b, f32x4 c) {
  return __builtin_amdgcn_mfma_f32_16x16x32_bf16(a, b, c, 0, 0, 0);
}

__device__ __forceinline__ short bf16_rne(float f) {
  unsigned u = __float_as_uint(f);
  unsigned r = (u + 0x7FFFu + ((u >> 16) & 1u)) >> 16;
  return (short)r;
}

__device__ __forceinline__ s16x8 rne8(const float* f) {
  s16x8 o;
#pragma unroll
  for (int i = 0; i < 8; ++i) o[i] = bf16_rne(f[i]);
  return o;
}

__device__ __forceinline__ void split8(const float* f, s16x8& hi, s16x8& lo) {
#pragma unroll
  for (int i = 0; i < 8; ++i) {
    unsigned ub = __float_as_uint(f[i]);
    hi[i] = (short)(ub >> 16);
    float hf = __uint_as_float(ub & 0xFFFF0000u);
    float lf = f[i] - hf;
    lo[i] = (short)(__float_as_uint(lf) >> 16);
  }
}

// ---------------------------------------------------------------------------
// Kernel A: fold FC into the input-side gate GEMM (fp32).
// ---------------------------------------------------------------------------
__global__ __launch_bounds__(256) void prep_kernel(
    const float* __restrict__ W_fc, const float* __restrict__ b_fc,
    const float* __restrict__ W_ih, const float* __restrict__ b_ih,
    const float* __restrict__ b_hh,
    float* __restrict__ wsW, float* __restrict__ wsB) {
  __shared__ float fc[H * D_INP];
  __shared__ float bfc[H];
  const int u = threadIdx.x;
  for (int i = u; i < H * D_INP; i += 256) fc[i] = W_fc[i];
  if (u < H) bfc[u] = b_fc[u];
  __syncthreads();

  float wih[H];
#pragma unroll
  for (int i = 0; i < H; ++i) wih[i] = W_ih[u * H + i];

  for (int k = 0; k < D_INP; ++k) {
    float s = 0.f;
#pragma unroll
    for (int i = 0; i < H; ++i) s = fmaf(wih[i], fc[i * D_INP + k], s);
    wsW[u * 32 + k] = s;
  }
  wsW[u * 32 + 30] = 0.f;
  wsW[u * 32 + 31] = 0.f;

  float bb = b_ih[u] + b_hh[u];
#pragma unroll
  for (int i = 0; i < H; ++i) bb = fmaf(wih[i], bfc[i], bb);
  wsB[u] = bb;
}

// ---------------------------------------------------------------------------
// Kernel B: MFMA LSTM. 64 blocks x 256 threads; block owns 16 batch rows.
// Wave w owns N-tiles {w,w+4,w+8,w+12}: all 4 gates of cols 16w..16w+16
// co-located per lane. Single-plane RNE bf16, log2e-prescaled weights.
// Pipelined: x-side MFMAs (accx) computed at the PREVIOUS iteration's tail;
// post-barrier chain = ds_read h -> 8 h-MFMAs -> acts -> h-write.
// Per-step barrier is lgkm-only (LDS_BARRIER).
// ---------------------------------------------------------------------------
__global__ __launch_bounds__(256, 1) void lstm_mfma(
    const float* __restrict__ x, const float* __restrict__ W_hh,
    const float* __restrict__ wsW, const float* __restrict__ wsB,
    const float* __restrict__ W_last, float* __restrict__ out) {

  __shared__ short xa[2][TCH][64][8];      // x A-frags RNE bf16, 16 KB
  __shared__ short hpl[2][MB][72];         // h bf16 plane, dbuf, 4.6 KB
  __shared__ float logitsT[NSEQ + 1][MB];  // logit of h_{t-1} at slot t

  const int u   = threadIdx.x;
  const int w   = u >> 6;
  const int l   = u & 63;
  const int low = l & 15;
  const int q   = l >> 4;
  const int b0  = blockIdx.x * MB;

  // ---- B-frags: single-plane RNE (gates), 2-term (logit) ----
  s16x8 whh[4][2], wcb[4], wl_h[2], wl_l[2];
  float biasv[4];
#pragma unroll
  for (int g = 0; g < 4; ++g) {
    const float sc = (g == 2) ? (2.0f * L2E) : L2E;
    const int n = 64 * g + 16 * w + low;
#pragma unroll
    for (int kt = 0; kt < 2; ++kt) {
      float tmp[8];
      const float* p = W_hh + n * H + kt * 32 + q * 8;
#pragma unroll
      for (int j = 0; j < 8; ++j) tmp[j] = p[j] * sc;
      whh[g][kt] = rne8(tmp);
    }
    {
      float tmp[8];
      const float* p = wsW + n * 32 + q * 8;
#pragma unroll
      for (int j = 0; j < 8; ++j) tmp[j] = p[j] * sc;
      wcb[g] = rne8(tmp);
    }
    biasv[g] = wsB[n] * sc;
  }
#pragma unroll
  for (int kt = 0; kt < 2; ++kt) {
    float tmp[8];
#pragma unroll
    for (int j = 0; j < 8; ++j)
      tmp[j] = (low == 0) ? W_last[kt * 32 + q * 8 + j] : 0.0f;
    split8(tmp, wl_h[kt], wl_l[kt]);
  }

  // zero h planes
  for (int i = u; i < 2 * MB * 72 / 2; i += 256) ((int*)hpl)[i] = 0;

  // ---- x staging: thread u builds dest-lane l's 16B A-frag row ----
  const float* xrow = x + (size_t)(b0 + low) * NSEQ * D_INP + q * 8;
  float xv[2][8];
  auto stage_load = [&](int t0) {
#pragma unroll
    for (int c = 0; c < 2; ++c) {
      const float* p = xrow + (size_t)(t0 + 2 * w + c) * D_INP;
      float2 v0 = *(const float2*)(p);
      float2 v1 = *(const float2*)(p + 2);
      float2 v2 = *(const float2*)(p + 4);
      float2 v3 = (q < 3) ? *(const float2*)(p + 6) : make_float2(0.f, 0.f);
      xv[c][0] = v0.x; xv[c][1] = v0.y; xv[c][2] = v1.x; xv[c][3] = v1.y;
      xv[c][4] = v2.x; xv[c][5] = v2.y; xv[c][6] = v3.x; xv[c][7] = v3.y;
    }
  };
  auto stage_write = [&](int buf) {
#pragma unroll
    for (int c = 0; c < 2; ++c) {
      const int s = 2 * w + c;
      *(s16x8*)&xa[buf][s][l][0] = rne8(xv[c]);  // b128, conflict-free
    }
  };

  stage_load(0);
  stage_write(0);
  __syncthreads();

  f32x4 c4 = {0.f, 0.f, 0.f, 0.f};

  // prologue: x-partial for t=0
  f32x4 accx[4];
  {
    s16x8 x0 = *(const s16x8*)&xa[0][0][l][0];
#pragma unroll
    for (int g = 0; g < 4; ++g) {
      f32x4 a = {biasv[g], biasv[g], biasv[g], biasv[g]};
      accx[g] = mfma16(x0, wcb[g], a);
    }
  }

  for (int t = 0; t < NSEQ; ++t) {
    const int tt = t & (TCH - 1);
    const int cb = (t >> 3) & 1;
    if (tt == 0 && t + TCH < NSEQ) stage_load(t + TCH);

    // ---- post-barrier critical chain: h frag + 8 h-MFMAs ----
    const short* hp = &hpl[(t + 1) & 1][low][0];
    s16x8 ah0 = *(const s16x8*)(hp + q * 8);
    s16x8 ah1 = *(const s16x8*)(hp + 32 + q * 8);

    // next step's x frag: content staged >=3 barriers ago; read early,
    // consumed at the tail (latency hidden behind the main body)
    s16x8 xn;
    if (t + 1 < NSEQ) {
      const int t1 = t + 1;
      xn = *(const s16x8*)&xa[(t1 >> 3) & 1][t1 & (TCH - 1)][l][0];
    }

    f32x4 acc[4];
#pragma unroll
    for (int g = 0; g < 4; ++g) {
      f32x4 a = mfma16(ah0, whh[g][0], accx[g]);
      acc[g] = mfma16(ah1, whh[g][1], a);
    }

    // logit_{t-1}: rotating extra N-tile
    if (w == (t & 3)) {
      f32x4 aL = {0.f, 0.f, 0.f, 0.f};
      aL = mfma16(ah0, wl_h[0], aL);
      aL = mfma16(ah1, wl_h[1], aL);
      f32x4 bL = {0.f, 0.f, 0.f, 0.f};
      bL = mfma16(ah0, wl_l[0], bL);
      bL = mfma16(ah1, wl_l[1], bL);
      aL = aL + bL;
      if (low == 0) *(f32x4*)&logitsT[t][q * 4] = aL;
    }

    // per-lane LSTM cell update (rows q*4+r, col 16w+low)
    short* hw = &hpl[t & 1][0][0];
#pragma unroll
    for (int r = 0; r < 4; ++r) {
      float gi = rcp_f(1.0f + EXP2(-acc[0][r]));
      float gf = rcp_f(1.0f + EXP2(-acc[1][r]));
      float gg = 1.0f - 2.0f * rcp_f(1.0f + EXP2(acc[2][r]));
      float go = rcp_f(1.0f + EXP2(-acc[3][r]));
      float cc = fmaf(gf, c4[r], gi * gg);
      c4[r] = cc;
      float h = go * (1.0f - 2.0f * rcp_f(1.0f + EXP2(cc * (2.0f * L2E))));
      hw[(q * 4 + r) * 72 + 16 * w + low] = bf16_rne(h);
    }

    // ---- tail (h-independent): x-partial for t+1, staging ----
    if (t + 1 < NSEQ) {
#pragma unroll
      for (int g = 0; g < 4; ++g) {
        f32x4 a = {biasv[g], biasv[g], biasv[g], biasv[g]};
        accx[g] = mfma16(xn, wcb[g], a);
      }
    }
    if (tt == 4 && t + 4 < NSEQ) stage_write(cb ^ 1);

    LDS_BARRIER();
  }

  // final logit from h_511 (in hpl[1])
  if (w == 0) {
    const short* hp = &hpl[1][low][0];
    s16x8 ah0 = *(const s16x8*)(hp + q * 8);
    s16x8 ah1 = *(const s16x8*)(hp + 32 + q * 8);
    f32x4 aL = {0.f, 0.f, 0.f, 0.f};
    aL = mfma16(ah0, wl_h[0], aL);
    aL = mfma16(ah1, wl_h[1], aL);
    f32x4 bL = {0.f, 0.f, 0.f, 0.f};
    bL = mfma16(ah0, wl_l[0], bL);
    bL = mfma16(ah1, wl_l[1], bL);
    aL = aL + bL;
    if (low == 0) *(f32x4*)&logitsT[NSEQ][q * 4] = aL;
  }
  __syncthreads();

  // ---- softmax over time: row m = u>>4, lanes cover t = (u&15) + 16s ----
  {
    const int m = u >> 4, li = u & 15;
    float lv[32];
    float mx = -3.0e38f;
#pragma unroll
    for (int s = 0; s < 32; ++s) {
      lv[s] = logitsT[1 + li + 16 * s][m];
      mx = fmaxf(mx, lv[s]);
    }
#pragma unroll
    for (int d = 1; d < 16; d <<= 1) mx = fmaxf(mx, __shfl_xor(mx, d, 16));
    float sum = 0.f;
#pragma unroll
    for (int s = 0; s < 32; ++s) { lv[s] = __expf(lv[s] - mx); sum += lv[s]; }
#pragma unroll
    for (int d = 1; d < 16; d <<= 1) sum += __shfl_xor(sum, d, 16);
    float inv = 1.0f / sum;
#pragma unroll
    for (int s = 0; s < 32; ++s)
      out[(size_t)(b0 + m) * NSEQ + li + 16 * s] = lv[s] * inv;
  }
}

// ---------------------------------------------------------------------------
extern "C" void kernel_launch(void* const* d_in, const int* in_sizes, int n_in,
                              void* d_out, int out_size, void* d_ws, size_t ws_size,
                              hipStream_t stream) {
  const float* x      = (const float*)d_in[0];
  const float* W_fc   = (const float*)d_in[1];
  const float* b_fc   = (const float*)d_in[2];
  const float* W_ih   = (const float*)d_in[3];
  const float* W_hh   = (const float*)d_in[4];
  const float* b_ih   = (const float*)d_in[5];
  const float* b_hh   = (const float*)d_in[6];
  const float* W_last = (const float*)d_in[7];
  // d_in[8] = b_last: cancels in softmax.

  float* out = (float*)d_out;
  float* wsW = (float*)d_ws;          // 256*32 floats
  float* wsB = wsW + 256 * 32;        // 256 floats

  prep_kernel<<<1, 256, 0, stream>>>(W_fc, b_fc, W_ih, b_ih, b_hh, wsW, wsB);
  lstm_mfma<<<B_SZ / MB, 256, 0, stream>>>(x, W_hh, wsW, wsB, W_last, out);
}